// Round 1
// baseline (154.313 us; speedup 1.0000x reference)
//
#include <hip/hip_runtime.h>

// Mean aggregator: out[n,:] = (1/K) * sum_k weight[idx[n,k],:]
// N = 100000 nodes, K = 10 neighbors, D = 128 feat (fp32).
//
// Layout: 32 lanes per node, each lane owns one float4 (4 floats) of the
// 128-float row. 32 lanes x 16B = 512B = one full row per half-wave --
// fully coalesced global_load_dwordx4. Index reads are half-wave-uniform
// (same address across the 32 lanes) -> broadcast from cache.

#define AGG_K 10
#define AGG_D 128

__global__ __launch_bounds__(256) void Aggregator_26439818674919_kernel(
    const float* __restrict__ weight,
    const int* __restrict__ nidx,
    float* __restrict__ out,
    int n_nodes) {
  const int tid  = blockIdx.x * 256 + threadIdx.x;
  const int node = tid >> 5;   // 32 lanes per node
  const int lane = tid & 31;   // lane*4 floats within the row
  if (node >= n_nodes) return;

  const int ibase = node * AGG_K;
  float4 acc = make_float4(0.f, 0.f, 0.f, 0.f);
#pragma unroll
  for (int k = 0; k < AGG_K; ++k) {
    const int idx = nidx[ibase + k];
    const float4 v = *reinterpret_cast<const float4*>(
        &weight[(size_t)idx * AGG_D + lane * 4]);
    acc.x += v.x; acc.y += v.y; acc.z += v.z; acc.w += v.w;
  }
  const float s = 1.0f / AGG_K;
  acc.x *= s; acc.y *= s; acc.z *= s; acc.w *= s;
  *reinterpret_cast<float4*>(&out[(size_t)node * AGG_D + lane * 4]) = acc;
}

extern "C" void kernel_launch(void* const* d_in, const int* in_sizes, int n_in,
                              void* d_out, int out_size, void* d_ws, size_t ws_size,
                              hipStream_t stream) {
  const float* weight = (const float*)d_in[0];
  const int*   nidx   = (const int*)d_in[1];
  float*       out    = (float*)d_out;

  const int n_nodes = in_sizes[1] / AGG_K;          // 100000
  const int total_threads = n_nodes * 32;           // 32 lanes per node
  const int blocks = (total_threads + 255) / 256;   // 12500

  Aggregator_26439818674919_kernel<<<blocks, 256, 0, stream>>>(
      weight, nidx, out, n_nodes);
}

// Round 3
// 154.262 us; speedup vs baseline: 1.0003x; 1.0003x over previous
//
#include <hip/hip_runtime.h>

// Mean aggregator: out[n,:] = (1/K) * sum_k weight[idx[n,k],:]
// N = 100000 nodes, K = 10 neighbors, D = 128 feat (fp32).
//
// 32 lanes per node, one float4 (16B) per lane = 512B/row per half-wave,
// fully coalesced global_load_dwordx4 gathers.
//
// R2 change (re-run; R2 bench lost to GPU acquisition timeout):
// non-temporal hints on the two streaming flows (output store, index
// loads) so the per-XCD 4MB L2 retains weight rows for the random gather
// instead of being churned by write-once/read-once data.

#define AGG_K 10
#define AGG_D 128

__global__ __launch_bounds__(256) void Aggregator_26439818674919_kernel(
    const float* __restrict__ weight,
    const int* __restrict__ nidx,
    float* __restrict__ out,
    int n_nodes) {
  const int tid  = blockIdx.x * 256 + threadIdx.x;
  const int node = tid >> 5;   // 32 lanes per node
  const int lane = tid & 31;   // lane*4 floats within the row
  if (node >= n_nodes) return;

  // Index loads: streamed once -> non-temporal (don't cache in L2).
  const int ibase = node * AGG_K;
  int idx[AGG_K];
#pragma unroll
  for (int k = 0; k < AGG_K; ++k) {
    idx[k] = __builtin_nontemporal_load(&nidx[ibase + k]);
  }

  // Gathers: the reusable working set (51MB table) -> normal cached loads.
  float4 acc = make_float4(0.f, 0.f, 0.f, 0.f);
#pragma unroll
  for (int k = 0; k < AGG_K; ++k) {
    const float4 v = *reinterpret_cast<const float4*>(
        &weight[(size_t)idx[k] * AGG_D + lane * 4]);
    acc.x += v.x; acc.y += v.y; acc.z += v.z; acc.w += v.w;
  }
  const float s = 1.0f / AGG_K;
  acc.x *= s; acc.y *= s; acc.z *= s; acc.w *= s;

  // Output store: write-once stream -> non-temporal, don't pollute L2.
  float* op = &out[(size_t)node * AGG_D + lane * 4];
  __builtin_nontemporal_store(acc.x, op + 0);
  __builtin_nontemporal_store(acc.y, op + 1);
  __builtin_nontemporal_store(acc.z, op + 2);
  __builtin_nontemporal_store(acc.w, op + 3);
}

extern "C" void kernel_launch(void* const* d_in, const int* in_sizes, int n_in,
                              void* d_out, int out_size, void* d_ws, size_t ws_size,
                              hipStream_t stream) {
  const float* weight = (const float*)d_in[0];
  const int*   nidx   = (const int*)d_in[1];
  float*       out    = (float*)d_out;

  const int n_nodes = in_sizes[1] / AGG_K;          // 100000
  const int total_threads = n_nodes * 32;           // 32 lanes per node
  const int blocks = (total_threads + 255) / 256;   // 12500

  Aggregator_26439818674919_kernel<<<blocks, 256, 0, stream>>>(
      weight, nidx, out, n_nodes);
}